// Round 1
// baseline (78.329 us; speedup 1.0000x reference)
//
#include <hip/hip_runtime.h>
#include <math.h>

#define NCLS   20
#define MCELLS 49
#define FEAT   30
#define ITEMF  1470   // MCELLS * FEAT

__device__ __forceinline__ float bcastf(float v, int l) {
  return __int_as_float(__builtin_amdgcn_readlane(__float_as_int(v), l));
}
__device__ __forceinline__ int bcasti(int v, int l) {
  return __builtin_amdgcn_readlane(v, l);
}

__global__ __launch_bounds__(256) void yolo_post(const float* __restrict__ x,
                                                 float* __restrict__ out,
                                                 int N) {
  const int wave = threadIdx.x >> 6;
  const int lane = threadIdx.x & 63;
  const int n = blockIdx.x * 4 + wave;

  __shared__ float ldsAll[4][ITEMF];
  __shared__ float keepAll[4][64];

  if (n >= N) return;  // per-wave uniform exit; no block-wide barriers used

  float* L  = ldsAll[wave];
  float* KS = keepAll[wave];

  // ---- stage input item to LDS (coalesced float2 loads) ----
  const float2* src = (const float2*)(x) + (size_t)n * (ITEMF / 2);
  float2* Ld = (float2*)L;
#pragma unroll
  for (int i = 0; i < 12; ++i) {
    int idx = lane + i * 64;
    if (idx < ITEMF / 2) Ld[idx] = src[idx];
  }
  __threadfence_block();  // order LDS writes before cross-lane reads (wave-synchronous)

  // ---- output section pointers (flat concat in return order) ----
  const size_t NM = (size_t)N * MCELLS;
  float* out0 = out;              // class_logits  N*M*20
  float* out1 = out0 + NM * 20;   // yolo_bboxes   N*M*5
  float* out2 = out1 + NM * 5;    // boxes         N*M*4
  float* out3 = out2 + NM * 4;    // scores        N*M
  float* out4 = out3 + NM;        // labels        N*M
  float* out5 = out4 + NM;        // keep_mask     N*M
  float* out6 = out5 + NM;        // reserve_mask  N*M

  // ---- class logits copy: LDS -> global, coalesced ----
  {
    float* dst = out0 + (size_t)n * (MCELLS * NCLS);
#pragma unroll
    for (int i = 0; i < 16; ++i) {
      int idx = lane + i * 64;
      if (idx < MCELLS * NCLS) {
        int c = idx / NCLS;
        int k = idx - c * NCLS;
        dst[idx] = L[c * FEAT + k];
      }
    }
  }

  // ---- per-cell compute (lane m = cell m) ----
  const int m = lane;
  const bool cellv = (m < MCELLS);
  const int base = m * FEAT;

  float labelF = 0.f;
  float bx = 0.f, by = 0.f, bw = 0.f, bh = 0.f, conf = 0.f;
  float x0 = 0.f, y0 = 0.f, x1 = 0.f, y1 = 0.f;
  bool reserve = false;

  if (cellv) {
    // label = argmax over 20 logits (first-max), == argmax(softmax)
    float bestv = L[base];
    int bl = 0;
#pragma unroll
    for (int c = 1; c < NCLS; ++c) {
      float v = L[base + c];
      if (v > bestv) { bestv = v; bl = c; }
    }
    labelF = (float)bl;

    // best bbox of 2 by confidence (argmax first-max: 1 only if strictly greater)
    float c0 = L[base + 24], c1 = L[base + 29];
    int bsel = (c1 > c0) ? 1 : 0;
    int bb = base + NCLS + bsel * 5;
    bx = L[bb]; by = L[bb + 1]; bw = L[bb + 2]; bh = L[bb + 3]; conf = L[bb + 4];

    float xg = (float)(m % 7), yg = (float)(m / 7);
    float cx = (bx + xg) / 7.0f, cy = (by + yg) / 7.0f;
    float hw = bw * 0.5f, hh = bh * 0.5f;
    x0 = fminf(fmaxf((cx - hw) * 448.0f, 0.f), 448.f);
    y0 = fminf(fmaxf((cy - hh) * 448.0f, 0.f), 448.f);
    x1 = fminf(fmaxf((cx + hw) * 448.0f, 0.f), 448.f);
    y1 = fminf(fmaxf((cy + hh) * 448.0f, 0.f), 448.f);
    reserve = (conf > 0.1f);

    // small per-cell outputs (direct per-lane stores)
    size_t ci = (size_t)n * MCELLS + m;
    float* yb = out1 + ci * 5;
    yb[0] = bx; yb[1] = by; yb[2] = bw; yb[3] = bh; yb[4] = conf;
    *(float4*)(out2 + ci * 4) = make_float4(x0, y0, x1, y1);
    out3[ci] = conf;
    out4[ci] = labelF;
    out6[ci] = reserve ? 1.0f : 0.0f;
  }

  // ---- NMS ----
  // max over all 49*4 clipped coords of this item
  float mx = cellv ? fmaxf(fmaxf(x0, y0), fmaxf(x1, y1)) : -INFINITY;
#pragma unroll
  for (int d = 1; d < 64; d <<= 1) mx = fmaxf(mx, __shfl_xor(mx, d));

  float off = labelF * (mx + 1.0f);  // invalid lanes: labelF=0, boxes=0 -> harmless
  float ox0 = x0 + off, oy0 = y0 + off, ox1 = x1 + off, oy1 = y1 + off;

  // stable descending sort by score (ties: ascending original index) — bitonic over 64 lanes
  float sv = (cellv && reserve) ? conf : -INFINITY;
  int sid = lane;
#pragma unroll
  for (int k = 2; k <= 64; k <<= 1) {
#pragma unroll
    for (int j = k >> 1; j >= 1; j >>= 1) {
      float ov = __shfl_xor(sv, j);
      int oid = __shfl_xor(sid, j);
      bool up = ((lane & k) == 0);
      bool lower = ((lane & j) == 0);
      bool selfPrec = (sv > ov) || ((sv == ov) && (sid < oid));
      if (selfPrec != (lower == up)) { sv = ov; sid = oid; }
    }
  }

  // gather sorted offset-boxes (lane j holds sorted position j, original index sid)
  float gx0 = __shfl(ox0, sid), gy0 = __shfl(oy0, sid);
  float gx1 = __shfl(ox1, sid), gy1 = __shfl(oy1, sid);
  float garea = fmaxf(gx1 - gx0, 0.f) * fmaxf(gy1 - gy0, 0.f);

  int vs = (sv != -INFINITY) ? 1 : 0;
  int supp = 0;
  float keepf = 0.f;

  for (int i = 0; i < MCELLS; ++i) {
    int sti = bcasti(vs | (supp << 1), i);
    bool keepi = (sti == 1);           // valid && !suppressed — wave-uniform
    if (lane == i && keepi) keepf = 1.0f;
    if (keepi) {
      float bix0 = bcastf(gx0, i), biy0 = bcastf(gy0, i);
      float bix1 = bcastf(gx1, i), biy1 = bcastf(gy1, i);
      float ia = bcastf(garea, i);
      float iw = fmaxf(fminf(bix1, gx1) - fmaxf(bix0, gx0), 0.f);
      float ih = fmaxf(fminf(biy1, gy1) - fmaxf(biy0, gy0), 0.f);
      float inter = iw * ih;
      float uni = ia + garea - inter;
      float iou = inter / fmaxf(uni, 1e-9f);
      if (iou > 0.7f && lane > i) supp = 1;
    }
  }

  // scatter keep flags back to original cell order via LDS
  KS[sid] = keepf;
  __threadfence_block();
  if (cellv) out5[(size_t)n * MCELLS + m] = KS[m];
}

extern "C" void kernel_launch(void* const* d_in, const int* in_sizes, int n_in,
                              void* d_out, int out_size, void* d_ws, size_t ws_size,
                              hipStream_t stream) {
  const float* x = (const float*)d_in[0];
  float* out = (float*)d_out;
  int N = in_sizes[0] / ITEMF;
  int grid = (N + 3) / 4;
  yolo_post<<<grid, 256, 0, stream>>>(x, out, N);
}

// Round 2
// 42.175 us; speedup vs baseline: 1.8573x; 1.8573x over previous
//
#include <hip/hip_runtime.h>
#include <math.h>

#define NCLS   20
#define MCELLS 49
#define FEAT   30
#define ITEMF  1470   // MCELLS * FEAT

typedef unsigned long long u64;
typedef unsigned int u32;

__device__ __forceinline__ float bcastf(float v, int l) {
  return __int_as_float(__builtin_amdgcn_readlane(__float_as_int(v), l));
}
__device__ __forceinline__ int bcasti(int v, int l) {
  return __builtin_amdgcn_readlane(v, l);
}

__global__ __launch_bounds__(256) void yolo_post(const float* __restrict__ x,
                                                 float* __restrict__ out,
                                                 int N) {
  const int wave = threadIdx.x >> 6;
  const int lane = threadIdx.x & 63;
  const int n = blockIdx.x * 4 + wave;

  __shared__ float ldsAll[4][ITEMF];

  if (n >= N) return;  // per-wave uniform exit; no block-wide barriers used

  float* L = ldsAll[wave];

  // ---- stage input item to LDS (coalesced float2 loads) ----
  const float2* src = (const float2*)(x) + (size_t)n * (ITEMF / 2);
  float2* Ld = (float2*)L;
#pragma unroll
  for (int i = 0; i < 12; ++i) {
    int idx = lane + i * 64;
    if (idx < ITEMF / 2) Ld[idx] = src[idx];
  }
  __threadfence_block();  // order LDS writes before reads (wave-synchronous)

  // ---- output section pointers (flat concat in return order) ----
  const size_t NM = (size_t)N * MCELLS;
  float* out0 = out;              // class_logits  N*M*20
  float* out1 = out0 + NM * 20;   // yolo_bboxes   N*M*5
  float* out2 = out1 + NM * 5;    // boxes         N*M*4
  float* out3 = out2 + NM * 4;    // scores        N*M
  float* out4 = out3 + NM;        // labels        N*M
  float* out5 = out4 + NM;        // keep_mask     N*M
  float* out6 = out5 + NM;        // reserve_mask  N*M

  // ---- class logits copy: LDS -> global, coalesced ----
  {
    float* dst = out0 + (size_t)n * (MCELLS * NCLS);
#pragma unroll
    for (int i = 0; i < 16; ++i) {
      int idx = lane + i * 64;
      if (idx < MCELLS * NCLS) {
        int c = idx / NCLS;
        int k = idx - c * NCLS;
        dst[idx] = L[c * FEAT + k];
      }
    }
  }

  // ---- per-cell compute (lane m = cell m) ----
  const int m = lane;
  const bool cellv = (m < MCELLS);
  const int base = m * FEAT;

  int   labi = 0;
  float conf = 0.f;
  float x0 = 0.f, y0 = 0.f, x1 = 0.f, y1 = 0.f;
  bool reserve = false;

  if (cellv) {
    // label = argmax over 20 logits (first-max), == argmax(softmax)
    float bestv = L[base];
#pragma unroll
    for (int c = 1; c < NCLS; ++c) {
      float v = L[base + c];
      if (v > bestv) { bestv = v; labi = c; }
    }

    // best bbox of 2 by confidence (argmax first-max: 1 only if strictly greater)
    float c0 = L[base + 24], c1 = L[base + 29];
    int bsel = (c1 > c0) ? 1 : 0;
    int bb = base + NCLS + bsel * 5;
    float bx = L[bb], by = L[bb + 1], bw = L[bb + 2], bh = L[bb + 3];
    conf = L[bb + 4];

    float xg = (float)(m % 7), yg = (float)(m / 7);
    float cx = (bx + xg) / 7.0f, cy = (by + yg) / 7.0f;
    float hw = bw * 0.5f, hh = bh * 0.5f;
    x0 = fminf(fmaxf((cx - hw) * 448.0f, 0.f), 448.f);
    y0 = fminf(fmaxf((cy - hh) * 448.0f, 0.f), 448.f);
    x1 = fminf(fmaxf((cx + hw) * 448.0f, 0.f), 448.f);
    y1 = fminf(fmaxf((cy + hh) * 448.0f, 0.f), 448.f);
    reserve = (conf > 0.1f);

    // small per-cell outputs (direct per-lane stores)
    size_t ci = (size_t)n * MCELLS + m;
    float* yb = out1 + ci * 5;
    yb[0] = bx; yb[1] = by; yb[2] = bw; yb[3] = bh; yb[4] = conf;
    *(float4*)(out2 + ci * 4) = make_float4(x0, y0, x1, y1);
    out3[ci] = conf;
    out4[ci] = (float)labi;
    out6[ci] = reserve ? 1.0f : 0.0f;
  }

  // ================= NMS =================
  // Cross-class IoU is exactly 0 under the reference's class-offset scheme,
  // so the global greedy scan == independent per-class greedy scans.
  // Sort by (label asc, score desc, idx asc) via a single u64 key; invalid -> ~0.
  bool vld0 = cellv && reserve;
  u64 key;
  if (vld0) {
    u32 sb = __float_as_uint(conf);            // conf in [0,1): positive -> monotone bits
    u32 inv = 0x7FFFFFFFu - sb;                // descending score -> ascending field
    key = ((u64)labi << 37) | ((u64)inv << 6) | (u64)lane;
  } else {
    key = ~0ull;
  }

  // bitonic sort, 64 lanes, ascending, distinct keys
#pragma unroll
  for (int k = 2; k <= 64; k <<= 1) {
#pragma unroll
    for (int j = k >> 1; j >= 1; j >>= 1) {
      u64 ok = __shfl(key, lane ^ j);
      bool lower = (lane & j) == 0;
      bool asc = (lane & k) == 0;
      if ((key > ok) == (lower == asc)) key = ok;
    }
  }

  const int sid = (int)(key & 63);
  const bool valid = (key != ~0ull);
  const int slab = (int)((key >> 37) & 31);   // 31 for invalid

  // gather sorted coords
  float gx0 = __shfl(x0, sid), gy0 = __shfl(y0, sid);
  float gx1 = __shfl(x1, sid), gy1 = __shfl(y1, sid);
  float garea = fmaxf(gx1 - gx0, 0.f) * fmaxf(gy1 - gy0, 0.f);

  // parallel suppression-row masks: rotations while any real same-label pair
  // exists at distance d (same label => contiguous run after the sort).
  u64 rowm = 0;
  for (int d = 1; d < MCELLS; ++d) {
    int src = (lane + d) & 63;
    int plab = __shfl(slab, src);
    bool match = (plab == slab);
    u64 anyreal = __ballot(match && (slab != 31) && (lane + d < 64));
    if (anyreal == 0) break;
    float px0 = __shfl(gx0, src), py0 = __shfl(gy0, src);
    float px1 = __shfl(gx1, src), py1 = __shfl(gy1, src);
    float pa  = bcastf(garea, 0) * 0.f + __shfl(garea, src);  // keep simple: shfl area
    float iw = fmaxf(fminf(px1, gx1) - fmaxf(px0, gx0), 0.f);
    float ih = fmaxf(fminf(py1, gy1) - fmaxf(py0, gy0), 0.f);
    float inter = iw * ih;
    float uni = pa + garea - inter;
    bool ok = match && (inter > 0.7f * fmaxf(uni, 1e-9f));
    rowm |= ok ? (1ull << src) : 0ull;
  }

  // serial greedy scan — SALU bit ops + 2 readlanes per kept box
  u64 vmask = __ballot(valid);      // valids occupy lanes 0..V-1 (sorted first)
  int V = __popcll(vmask);
  u64 supp = 0, keep = 0;
  int rlo = (int)(rowm & 0xFFFFFFFFull);
  int rhi = (int)(rowm >> 32);
  for (int i = 0; i < V; ++i) {
    if (!((supp >> i) & 1ull)) {
      keep |= 1ull << i;
      u64 rm = ((u64)(u32)bcasti(rhi, i) << 32) | (u32)bcasti(rlo, i);
      supp |= rm;
    }
  }

  // scatter keep bit (sorted lane -> original cell lane) via ds_permute
  int keepbit = (int)((keep >> lane) & 1ull);
  int kf = __builtin_amdgcn_ds_permute(sid << 2, __float_as_int((float)keepbit));
  if (cellv) out5[(size_t)n * MCELLS + m] = __int_as_float(kf);
}

extern "C" void kernel_launch(void* const* d_in, const int* in_sizes, int n_in,
                              void* d_out, int out_size, void* d_ws, size_t ws_size,
                              hipStream_t stream) {
  const float* x = (const float*)d_in[0];
  float* out = (float*)d_out;
  int N = in_sizes[0] / ITEMF;
  int grid = (N + 3) / 4;
  yolo_post<<<grid, 256, 0, stream>>>(x, out, N);
}